// Round 7
// baseline (647.490 us; speedup 1.0000x reference)
//
#include <hip/hip_runtime.h>

// Soft-DTW forward, B=128, N=M=512, gamma=1.0, fp32.
// ROUND-16: coalesced staged loads. Post-mortem chain R9..R15: per-step
// cost is pinned at ~430-490cy across ALL geometries because the per-step
// load is a 64-distinct-line gather (64 lanes x 2KB-strided rows); 8-deep
// pipelining wants 512 lines in flight per wave >> CU miss-tracking ->
// gathers serialize at ~1 memory latency each. Fix = fewer lines per
// load, not more depth:
//   Lane 4a+b at step s loads row = sbase+T+11 - 256w - 16a (INDEPENDENT
//   of b), cols jb..jb+3  ->  4 consecutive lanes share one 64B line:
//   16 lines/instr (was 64), and each line of D is fetched EXACTLY ONCE
//   over the whole run (no L1-thrash refetch; effective traffic 4x lower).
//   row = (sbase+T+11) + fourb - jb, fourb = 4*(lane&3): the data lands
//   in the CONSUMING lane itself, 4b steps early (entry e = s+11+fourb
//   holds D[e-jb][jb..jb+3], consumed at steps e..e+3).
// The 4b time-skew is absorbed by a per-lane 16-slot LDS FIFO (stride
// 17 float4 = 272B -> 16B-aligned, bank-floor-even):
//   step s: (1) ds_write entry s+3+fourb = stage reg loaded 8 steps ago
//           (slot (e)&15; vmcnt(7)-style, NEVER drained);
//           (2) issue this step's coalesced load -> stage ring stg[T&7];
//           (3) ds_read entry s+3 (slot (T+3)&15 = compile-time offset)
//           -> reg ring buf[(T+3)&7], consumed from step s+3 on.
//   b=0 lanes forward write->read same slot same step: DS ops are
//   same-wave in-order -> correct. Slot-reuse margin is 4 steps in
//   steady state (entry e read at e-3, slot overwritten at e+1) and
//   verified for the prologue (entries 3..18 prefilled; 19..22 covered
//   by the prefilled stage ring at steps 4..7, overwriting slots whose
//   prior entries were read >=4 steps earlier).
// Everything else byte-identical to R15 (absmax=0 there): 2 waves x
// 4 cols/lane, skew-16 ring pipeline, volatile-asm ring/gx (no memory
// clobbers anywhere -> SROA keeps arrays in regs), per-wave DPP renorm,
// exact pow2 frame conversion, SELECT-killed w0 garbage, junk-at-consume
// (s-c >= tq), one lgkmcnt(0)+s_barrier per 16-step interval.
// D values are frame-independent -> the FIFO needs no renorm handling.
//
// PREDICTIONS: dur 186 -> 70-130us; VGPR 56 -> 100-140 (<=60 means
// promotion failed -> that becomes the target); VALUBusy 9->12-20%;
// FETCH_SIZE ~65MB unchanged. Fallback if >=150us with healthy VGPR:
// memory theory wrong -> isolate with constant-d no-load variant.

#define BB 128
#define NN 512
#define MM 512
#define L2E 1.4426950408889634f
#define LN2 0.6931471805599453f

typedef float f32x4 __attribute__((ext_vector_type(4)));

__device__ __forceinline__ int iclamp(int x, int lo, int hi) {
    return x < lo ? lo : (x > hi ? hi : x);
}

template<int CTRL>
__device__ __forceinline__ float dpp_fmax(float v) {
    const int s = __builtin_amdgcn_update_dpp(
        __float_as_int(v), __float_as_int(v), CTRL, 0xF, 0xF, false);
    return __builtin_fmaxf(v, __int_as_float(s));
}

// lane k <- lane k-1 (wave_shr:1), VALU-speed; lane 0 keeps old (unused).
__device__ __forceinline__ float dpp_shr1(float v) {
    const int s = __builtin_amdgcn_update_dpp(
        __float_as_int(v), __float_as_int(v), 0x138, 0xF, 0xF, false);
    return __int_as_float(s);
}

// One DP step: 4 cells (cols jb..jb+3) on diagonal s = sbase + T.
template<int T>
__device__ __forceinline__ void dostep(
    const float* __restrict__ Db, const int lane, const bool wpub,
    const int jb, const int fj, const int fourb, const int sbase, const int tq,
    float (&r1)[4], float (&r2)[4], float4 (&buf)[8], float4 (&stg)[8],
    float4* fifoL,
    float& sh, float& shprev, float& bl, float& bd,
    const f32x4 (&bv)[4], const unsigned wrA)
{
    const int s = sbase + T;
    // (1) FIFO write-out: the load issued 8 steps ago = entry s+3+fourb.
    //     (reads old stg[T&7] before (2) overwrites it; compiler emits
    //      the vmcnt(7)-style wait — queue never drained)
    fifoL[(T + 3 + fourb) & 15] = stg[T & 7];
    // (2) coalesced global load (entry s+11+fourb): row independent of
    //     lane&3 -> lanes 4a..4a+3 share one 64B line (16 lines/instr).
    {
        const int row = iclamp((sbase + (T + 11)) + fj, 0, NN - 1);
        stg[T & 7] = *(const float4*)(Db + ((row << 9) + jb));
    }
    // (3) FIFO read entry s+3 -> reg ring (compile-time slot offset).
    buf[(T + 3) & 7] = fifoL[(T + 3) & 15];

    float nv1, nv2, nv3;
    {   // c = 3 (entry s-3, component w)
        const float d = buf[(T + 5) & 7].w;
        float wg = __builtin_amdgcn_exp2f(-L2E * d);
        wg = ((s - 3) >= tq) ? 0.0f : wg;          // i = s-3-jb >= 512
        nv3 = wg * ((r1[3] + r1[2]) + r2[2]);
    }
    {   // c = 2
        const float d = buf[(T + 6) & 7].z;
        float wg = __builtin_amdgcn_exp2f(-L2E * d);
        wg = ((s - 2) >= tq) ? 0.0f : wg;
        nv2 = wg * ((r1[2] + r1[1]) + r2[1]);
    }
    {   // c = 1
        const float d = buf[(T + 7) & 7].y;
        float wg = __builtin_amdgcn_exp2f(-L2E * d);
        wg = ((s - 1) >= tq) ? 0.0f : wg;
        nv1 = wg * ((r1[1] + r1[0]) + r2[0]);
    }
    // boundary publish (wave0 lane63): ring[s&63] <- nv3; retired by the
    // interval-end lgkmcnt(0); read by wave1 one interval later.
    if (wpub)
        asm volatile("ds_write_b32 %0, %1 offset:%2"
                     :: "v"(wrA), "v"(nv3), "n"(T * 4));
    float nv0;
    {   // c = 0 (consumes intra-wave sh/shprev or cross-wave bl/bd)
        const float d = buf[T & 7].x;
        const float lf = (lane == 0) ? bl : sh;
        const float dg = (lane == 0) ? bd : shprev;
        float wg = __builtin_amdgcn_exp2f(-L2E * d);
        wg = (s >= tq) ? 0.0f : wg;
        nv0 = wg * ((r1[0] + lf) + dg);
    }

    r2[0] = r1[0]; r2[1] = r1[1]; r2[2] = r1[2]; r2[3] = r1[3];
    r1[0] = nv0;   r1[1] = nv1;   r1[2] = nv2;   r1[3] = nv3;
    bd = bl;
    bl = bv[T >> 2][T & 3];    // boundary(s), consumed at step s+1
    shprev = sh;
    sh = dpp_shr1(nv3);        // neighbor handoff, consumed next step
}

// Per-wave renorm: rescale own state by 2^-ex, ex = exponent of wave max.
__device__ __forceinline__ void renorm_local(
    float (&r1)[4], float (&r2)[4], float& sh, float& shprev,
    float& bl, float& bd, float& gexp)
{
    float m = __builtin_fmaxf(__builtin_fmaxf(r1[0], r1[1]),
                              __builtin_fmaxf(r1[2], r1[3]));
    m = dpp_fmax<0x111>(m);   // row_shr:1
    m = dpp_fmax<0x112>(m);   // row_shr:2
    m = dpp_fmax<0x114>(m);   // row_shr:4
    m = dpp_fmax<0x118>(m);   // row_shr:8
    m = dpp_fmax<0x142>(m);   // row_bcast:15
    m = dpp_fmax<0x143>(m);   // row_bcast:31 -> lane 63 = wave max
    const int mb = __builtin_amdgcn_readlane(__float_as_int(m), 63);
    const int eb = (mb >> 23) & 255;
    const int ex = (eb > 0 && eb < 255) ? (eb - 127) : 0;  // 0/denorm/inf: hold
    const float rs = __int_as_float((127 - ex) << 23);     // exact 2^-ex
    r1[0] *= rs; r1[1] *= rs; r1[2] *= rs; r1[3] *= rs;
    r2[0] *= rs; r2[1] *= rs; r2[2] *= rs; r2[3] *= rs;
    sh *= rs; shprev *= rs;
    bl *= rs;   // interval-crossing handoffs: compose frames exactly
    bd *= rs;
    gexp += (float)ex;                                     // int-exact in fp32
}

#define DSTEP(T) dostep<T>(Db,lane,wpub,jb,fj,fourb,sbase,tq,r1,r2,buf,stg,fifoL,sh,shprev,bl,bd,bv,wrA);

__launch_bounds__(128, 1)
__global__ void softdtw_stg(const float* __restrict__ D, float* __restrict__ out) {
    const int b = blockIdx.x;
    const int tid = (int)threadIdx.x;
    const int w = tid >> 6;                  // wave 0..1
    const int lane = tid & 63;
    const int jb = (w << 8) + (lane << 2);   // global column base (4 cols/lane)
    const int fourb = (lane & 3) << 2;       // 4*(lane&3): the line-share skew
    const int fj = fourb - jb;               // per-lane row-offset constant
    const int tq = jb + NN;                  // junk: s - c >= tq  <=>  i >= NN
    const bool wpub = (w == 0) && (lane == 63);
    const float* __restrict__ Db = D + (size_t)b * (NN * MM);

    // per-lane FIFO: 16 slots used, stride 17 float4 (272B: 16B-aligned,
    // bank spread at the b128 throughput floor). ~35KB total.
    __shared__ float4 fifoS[2][64][17];
    // cross-wave ring (64 slots) + gx (2 parity slots) — raw-asm region.
    __shared__ __align__(16) float ldsF[66];
    float4* fifoL = &fifoS[w][lane][0];
    const unsigned ldsbase = (unsigned)(size_t)(void*)ldsF;
    const unsigned ringb = ldsbase;
    const unsigned gxb   = ldsbase + 256u;

    float r1[4] = {0.0f, 0.0f, 0.0f, 0.0f};
    float r2[4] = {0.0f, 0.0f, 0.0f, 0.0f};
    float4 buf[8];
    float4 stg[8];
    #pragma unroll
    for (int i = 0; i < 8; ++i) buf[i] = make_float4(0.f, 0.f, 0.f, 0.f);

    // ---- prologue ----
    // FIFO entries 3..18 (slots e&15: all 16 distinct), two reg batches.
    {
        float4 pb[8];
        #pragma unroll
        for (int e = 3; e < 11; ++e) {
            const int row = iclamp(e - jb, 0, NN - 1);
            pb[e - 3] = *(const float4*)(Db + ((row << 9) + jb));
        }
        #pragma unroll
        for (int e = 3; e < 11; ++e) fifoL[e & 15] = pb[e - 3];
        #pragma unroll
        for (int e = 11; e < 19; ++e) {
            const int row = iclamp(e - jb, 0, NN - 1);
            pb[e - 11] = *(const float4*)(Db + ((row << 9) + jb));
        }
        #pragma unroll
        for (int e = 11; e < 19; ++e) fifoL[e & 15] = pb[e - 11];
    }
    // stage ring prefill: stg[j] = entry j+3+fourb (ds-written at step j).
    #pragma unroll
    for (int j = 0; j < 8; ++j) {
        const int row = iclamp((j + 3) + fj, 0, NN - 1);
        stg[j] = *(const float4*)(Db + ((row << 9) + jb));
    }
    // reg-ring direct entries 0..2 (never pass through the FIFO).
    #pragma unroll
    for (int e = 0; e < 3; ++e) {
        const int row = iclamp(e - jb, 0, NN - 1);
        buf[e] = *(const float4*)(Db + ((row << 9) + jb));
    }

    float sh = 0.0f, shprev = 0.0f;
    float bl = 0.0f;                         // cross-wave left (wave0: always 0)
    float bd = (w == 0) ? 1.0f : 0.0f;       // seed E(R[0,0]=0)=1 at (0,0); then 0
    float gexp = 0.0f;                       // per-wave frame exponent

    // 65 global intervals; wave w active for k in [w, w+63]
    // (local diagonals sbase = 16(k-w)). One barrier per interval.
    #pragma unroll 1
    for (int k = 0; k < 65; ++k) {
        // BOTH waves: retire LDS writes, then barrier. vmcnt untouched.
        asm volatile("s_waitcnt lgkmcnt(0)\n\ts_barrier");
        const int kw = k - w;
        if (kw < 0 || kw > 63) continue;     // wave-uniform branch
        const int sbase = kw << 4;

        // batch-read boundary chunk (diagonals sbase..sbase+15, written by
        // wave0 during interval k-1 under one frame) + that frame.
        f32x4 q0, q1, q2, q3; float gxp;
        {
            const unsigned raddr = ringb + (((unsigned)sbase & 63u) << 2);
            const unsigned gaddr = gxb + (((unsigned)(k - 1) & 1u) << 2);
            asm volatile(
                "ds_read_b128 %0, %5\n\t"
                "ds_read_b128 %1, %5 offset:16\n\t"
                "ds_read_b128 %2, %5 offset:32\n\t"
                "ds_read_b128 %3, %5 offset:48\n\t"
                "ds_read_b32  %4, %6\n\t"
                "s_waitcnt lgkmcnt(0)"
                : "=&v"(q0), "=&v"(q1), "=&v"(q2), "=&v"(q3), "=&v"(gxp)
                : "v"(raddr), "v"(gaddr));
        }

        renorm_local(r1, r2, sh, shprev, bl, bd, gexp);

        // publish my frame for this interval's ring writes (parity k&1;
        // read by wave1 at interval k+1; overwritten at k+2).
        if (wpub) {
            const unsigned ga = gxb + (((unsigned)k & 1u) << 2);
            asm volatile("ds_write_b32 %0, %1" :: "v"(ga), "v"(gexp));
        }

        // frame-convert chunk into my (post-renorm) frame; w==0 -> 0 via
        // SELECT (never multiply garbage into live values).
        float scale;
        {
            int dlt = (int)(gxp - gexp);     // both int-exact in fp32
            dlt = iclamp(dlt, -126, 126);
            scale = __int_as_float((127 + dlt) << 23);  // exact 2^dlt
        }
        const bool act = (w > 0);
        const f32x4 zz = {0.0f, 0.0f, 0.0f, 0.0f};
        f32x4 bv[4];
        bv[0] = act ? q0 * scale : zz;
        bv[1] = act ? q1 * scale : zz;
        bv[2] = act ? q2 * scale : zz;
        bv[3] = act ? q3 * scale : zz;

        const unsigned wrA = ringb + (((unsigned)sbase & 63u) << 2);

        if (kw < 63) {
            DSTEP(0)  DSTEP(1)  DSTEP(2)  DSTEP(3)
            DSTEP(4)  DSTEP(5)  DSTEP(6)  DSTEP(7)
            DSTEP(8)  DSTEP(9)  DSTEP(10) DSTEP(11)
            DSTEP(12) DSTEP(13) DSTEP(14) DSTEP(15)
        } else {
            // tail interval: diagonals 1008..1022 (15 steps)
            DSTEP(0)  DSTEP(1)  DSTEP(2)  DSTEP(3)
            DSTEP(4)  DSTEP(5)  DSTEP(6)  DSTEP(7)
            DSTEP(8)  DSTEP(9)  DSTEP(10) DSTEP(11)
            DSTEP(12) DSTEP(13) DSTEP(14)
        }
    }

    // final cell (511,511): wave1, lane63, c=3 at diagonal 1022.
    // E_true = r1[3] * 2^gexp;  R = -(log2(r1[3]) + gexp) * ln2
    if (w == 1 && lane == 63) {
        out[b] = -(__builtin_amdgcn_logf(r1[3]) + gexp) * LN2;
    }
}

extern "C" void kernel_launch(void* const* d_in, const int* in_sizes, int n_in,
                              void* d_out, int out_size, void* d_ws, size_t ws_size,
                              hipStream_t stream) {
    const float* D = (const float*)d_in[0];
    float* out = (float*)d_out;
    softdtw_stg<<<BB, 128, 0, stream>>>(D, out);
}